// Round 6
// baseline (25930.984 us; speedup 1.0000x reference)
//
#include <hip/hip_runtime.h>

#define T_SEQ 8192
#define POISON 0xAAAAAAAAu

typedef float vfloat4 __attribute__((ext_vector_type(4)));

static __device__ __forceinline__ float sigm(float x)  { return 1.0f / (1.0f + __expf(-x)); }
static __device__ __forceinline__ float tanhq(float x) { return 1.0f - 2.0f / (__expf(2.0f * x) + 1.0f); }

// Agent(device)-scope relaxed store -> L3 (device-coherent). R5-proven.
static __device__ __forceinline__ void astore(unsigned* p, float v) {
  __hip_atomic_store(p, __float_as_uint(v), __ATOMIC_RELAXED, __HIP_MEMORY_SCOPE_AGENT);
}
// Agent-scope 16B poll (sc1 ONLY = device scope; R4 lesson: sc0+sc1 = system
// scope -> HBM traffic). 4 words validated per line-request.
static __device__ __forceinline__ vfloat4 pollLoad4(const float* p) {
  vfloat4 v;
  asm volatile("global_load_dwordx4 %0, %1, off sc1\n\ts_waitcnt vmcnt(0)"
               : "=v"(v) : "v"(p) : "memory");
  return v;
}
static __device__ __forceinline__ bool valid4(vfloat4 v) {
  return (__float_as_uint(v[0]) != POISON) && (__float_as_uint(v[1]) != POISON) &&
         (__float_as_uint(v[2]) != POISON) && (__float_as_uint(v[3]) != POISON);
}

// LDS pad-swizzle (R3-proven: SQ_LDS_BANK_CONFLICT=0): word i -> i + (i>>6)*4.
#define SWZ(i) ((i) + (((i) >> 6) << 2))

// 64 named float4 weight locals = 256 floats/thread (4 gate-rows x 64-fl chunk),
// pinned INSIDE the step loop (R5 lesson: only in-loop "+v" pins survive).
#define WJ(X,r) X(r,0) X(r,1) X(r,2) X(r,3) X(r,4) X(r,5) X(r,6) X(r,7) \
                X(r,8) X(r,9) X(r,10) X(r,11) X(r,12) X(r,13) X(r,14) X(r,15)
#define WALL(X) WJ(X,0) WJ(X,1) WJ(X,2) WJ(X,3)
#define DECLW(r,j) float4 W_##r##_##j = wr##r[j];
#define PINW(r,j)  asm volatile("" : "+v"(W_##r##_##j.x), "+v"(W_##r##_##j.y), \
                                     "+v"(W_##r##_##j.z), "+v"(W_##r##_##j.w));
#define FMAJ(r,j)  { a##r = __builtin_fmaf(W_##r##_##j.x, hv.x, a##r); \
                     a##r = __builtin_fmaf(W_##r##_##j.y, hv.y, a##r); \
                     a##r = __builtin_fmaf(W_##r##_##j.z, hv.z, a##r); \
                     a##r = __builtin_fmaf(W_##r##_##j.w, hv.w, a##r); }
#define DOJ(j) { float4 hv = hp4[j]; FMAJ(0,j) FMAJ(1,j) FMAJ(2,j) FMAJ(3,j) }
#define DOALL  DOJ(0) DOJ(1) DOJ(2) DOJ(3) DOJ(4) DOJ(5) DOJ(6) DOJ(7) \
               DOJ(8) DOJ(9) DOJ(10) DOJ(11) DOJ(12) DOJ(13) DOJ(14) DOJ(15)

// blocks 0..15  : layer 0. 32 h/block; thread = (h-group 0..31, chunk q 0..7).
// blocks 16..47 : layer 1. 16 h/block; thread = (h-group 0..15, chunk q 0..15).
// Each thread: 4 gate rows (i,f,g,o) of one h-index, 64-float K-chunk each.
// LDS reads are 8-way (L0) / 4-way+2-addr (L1) broadcast -> ~3x less LDS-pipe.
__global__ __launch_bounds__(256, 1) void lstm_main(
    const float* __restrict__ input_seq,
    const float* __restrict__ w_ih0, const float* __restrict__ w_hh0,
    const float* __restrict__ b_ih0, const float* __restrict__ b_hh0,
    const float* __restrict__ w_ih1, const float* __restrict__ w_hh1,
    const float* __restrict__ b_ih1, const float* __restrict__ b_hh1,
    float* __restrict__ h0buf, float* __restrict__ h1buf)
{
  __shared__ float xin[T_SEQ];                   // 32 KB (layer-0 blocks only)
  __shared__ __align__(16) float hb[2][1088];    // double-buffered swizzled h rows
  const int tid  = threadIdx.x;
  const int wg   = blockIdx.x;
  int gd = 1 << 22;                              // poll budget: break, don't hang

  if (wg < 16) {
    // ================= layer 0 (K=512) =================
    for (int i = tid; i < T_SEQ; i += 256) xin[i] = input_seq[i];
    const int q    = tid & 7;                    // K-chunk (64 floats)
    const int grp  = tid >> 3;                   // h-group 0..31
    const int hidx = wg * 32 + grp;              // owned h index
    const float4* wr0 = (const float4*)(w_hh0 + (size_t)(0 * 512 + hidx) * 512 + q * 64);
    const float4* wr1 = (const float4*)(w_hh0 + (size_t)(1 * 512 + hidx) * 512 + q * 64);
    const float4* wr2 = (const float4*)(w_hh0 + (size_t)(2 * 512 + hidx) * 512 + q * 64);
    const float4* wr3 = (const float4*)(w_hh0 + (size_t)(3 * 512 + hidx) * 512 + q * 64);
    WALL(DECLW)
    const float wx0 = w_ih0[0 * 512 + hidx], wx1 = w_ih0[1 * 512 + hidx];
    const float wx2 = w_ih0[2 * 512 + hidx], wx3 = w_ih0[3 * 512 + hidx];
    const float b0 = b_ih0[0 * 512 + hidx] + b_hh0[0 * 512 + hidx];
    const float b1 = b_ih0[1 * 512 + hidx] + b_hh0[1 * 512 + hidx];
    const float b2 = b_ih0[2 * 512 + hidx] + b_hh0[2 * 512 + hidx];
    const float b3 = b_ih0[3 * 512 + hidx] + b_hh0[3 * 512 + hidx];
    float c = 0.0f;                              // valid in q==0 lanes
    __syncthreads();                             // xin ready

    for (int t = 0; t < T_SEQ; ++t) {
      WALL(PINW)                                 // loop-carried: no weight remat
      float* hl = hb[t & 1];
      if (tid < 128) {                           // 2 waves stage the 512-fl row
        vfloat4 v;
        if (t == 0) {
          v[0] = v[1] = v[2] = v[3] = 0.0f;
        } else {
          const float* src = h0buf + (size_t)(t - 1) * 512 + 4 * tid;
          for (;;) {
            v = pollLoad4(src);
            if (valid4(v)) break;
            if (--gd <= 0) break;
            __builtin_amdgcn_s_sleep(1);
          }
        }
        *(vfloat4*)&hl[SWZ(4 * tid)] = v;
      }
      __syncthreads();
      const float4* hp4 = (const float4*)(hl + q * 68);
      float a0 = 0.f, a1 = 0.f, a2 = 0.f, a3 = 0.f;
      DOALL
      a0 += __shfl_xor(a0, 1); a0 += __shfl_xor(a0, 2); a0 += __shfl_xor(a0, 4);
      a1 += __shfl_xor(a1, 1); a1 += __shfl_xor(a1, 2); a1 += __shfl_xor(a1, 4);
      a2 += __shfl_xor(a2, 1); a2 += __shfl_xor(a2, 2); a2 += __shfl_xor(a2, 4);
      a3 += __shfl_xor(a3, 1); a3 += __shfl_xor(a3, 2); a3 += __shfl_xor(a3, 4);
      const float xt = xin[t];
      float i_ = sigm(a0 + b0 + wx0 * xt);
      float f_ = sigm(a1 + b1 + wx1 * xt);
      float g_ = tanhq(a2 + b2 + wx2 * xt);
      float o_ = sigm(a3 + b3 + wx3 * xt);
      c = f_ * c + i_ * g_;
      float h = o_ * tanhq(c);
      if (q == 0)
        astore((unsigned*)(h0buf + (size_t)t * 512 + hidx), h);
    }
  } else {
    // ================= layer 1 (K=1024: h0|h1) =================
    const int wg1  = wg - 16;                    // 0..31
    const int q    = tid & 15;                   // 0..7 -> w_ih1/h0, 8..15 -> w_hh1/h1
    const int grp  = tid >> 4;                   // h-group 0..15
    const int hidx = wg1 * 16 + grp;
    const float* base0 = (q < 8) ? (w_ih1 + (size_t)(0 * 512 + hidx) * 512 + q * 64)
                                 : (w_hh1 + (size_t)(0 * 512 + hidx) * 512 + (q - 8) * 64);
    const float* base1 = (q < 8) ? (w_ih1 + (size_t)(1 * 512 + hidx) * 512 + q * 64)
                                 : (w_hh1 + (size_t)(1 * 512 + hidx) * 512 + (q - 8) * 64);
    const float* base2 = (q < 8) ? (w_ih1 + (size_t)(2 * 512 + hidx) * 512 + q * 64)
                                 : (w_hh1 + (size_t)(2 * 512 + hidx) * 512 + (q - 8) * 64);
    const float* base3 = (q < 8) ? (w_ih1 + (size_t)(3 * 512 + hidx) * 512 + q * 64)
                                 : (w_hh1 + (size_t)(3 * 512 + hidx) * 512 + (q - 8) * 64);
    const float4* wr0 = (const float4*)base0;
    const float4* wr1 = (const float4*)base1;
    const float4* wr2 = (const float4*)base2;
    const float4* wr3 = (const float4*)base3;
    WALL(DECLW)
    const float b0 = b_ih1[0 * 512 + hidx] + b_hh1[0 * 512 + hidx];
    const float b1 = b_ih1[1 * 512 + hidx] + b_hh1[1 * 512 + hidx];
    const float b2 = b_ih1[2 * 512 + hidx] + b_hh1[2 * 512 + hidx];
    const float b3 = b_ih1[3 * 512 + hidx] + b_hh1[3 * 512 + hidx];
    const int chunkOff = (q < 8) ? q * 68 : 544 + (q - 8) * 68;  // 544 = SWZ(512)
    float c = 0.0f;                              // valid in q==0 lanes
    __syncthreads();

    for (int t = 0; t < T_SEQ; ++t) {
      WALL(PINW)                                 // loop-carried: no weight remat
      float* hl = hb[t & 1];
      vfloat4 v;
      if (tid < 128) {                           // h0[t] (always polled)
        const float* src = h0buf + (size_t)t * 512 + 4 * tid;
        for (;;) {
          v = pollLoad4(src);
          if (valid4(v)) break;
          if (--gd <= 0) break;
          __builtin_amdgcn_s_sleep(1);
        }
        *(vfloat4*)&hl[SWZ(4 * tid)] = v;
      } else {                                   // h1[t-1] (zeros at t==0)
        const int p2 = tid - 128;
        if (t == 0) {
          v[0] = v[1] = v[2] = v[3] = 0.0f;
        } else {
          const float* src = h1buf + (size_t)(t - 1) * 512 + 4 * p2;
          for (;;) {
            v = pollLoad4(src);
            if (valid4(v)) break;
            if (--gd <= 0) break;
            __builtin_amdgcn_s_sleep(1);
          }
        }
        *(vfloat4*)&hl[544 + SWZ(4 * p2)] = v;
      }
      __syncthreads();
      const float4* hp4 = (const float4*)(hl + chunkOff);
      float a0 = 0.f, a1 = 0.f, a2 = 0.f, a3 = 0.f;
      DOALL
      a0 += __shfl_xor(a0, 1); a0 += __shfl_xor(a0, 2); a0 += __shfl_xor(a0, 4); a0 += __shfl_xor(a0, 8);
      a1 += __shfl_xor(a1, 1); a1 += __shfl_xor(a1, 2); a1 += __shfl_xor(a1, 4); a1 += __shfl_xor(a1, 8);
      a2 += __shfl_xor(a2, 1); a2 += __shfl_xor(a2, 2); a2 += __shfl_xor(a2, 4); a2 += __shfl_xor(a2, 8);
      a3 += __shfl_xor(a3, 1); a3 += __shfl_xor(a3, 2); a3 += __shfl_xor(a3, 4); a3 += __shfl_xor(a3, 8);
      float i_ = sigm(a0 + b0);
      float f_ = sigm(a1 + b1);
      float g_ = tanhq(a2 + b2);
      float o_ = sigm(a3 + b3);
      c = f_ * c + i_ * g_;
      float h = o_ * tanhq(c);
      if (q == 0)
        astore((unsigned*)(h1buf + (size_t)t * 512 + hidx), h);
    }
  }
}

// ---------------- MLP head on the final hidden state ----------------
__global__ void lstm_head(const float* __restrict__ h1buf,
                          const float* __restrict__ w1, const float* __restrict__ b1,
                          const float* __restrict__ w2, const float* __restrict__ b2,
                          float* __restrict__ out)
{
  const int lane = threadIdx.x;     // 64 threads
  const float* h2 = h1buf + (size_t)(T_SEQ - 1) * 512;
  float hv[8];
  #pragma unroll
  for (int k = 0; k < 8; ++k) hv[k] = h2[lane * 8 + k];
  float o = 0.0f;
  for (int r = 0; r < 20; ++r) {
    const float* wr = w1 + r * 512 + lane * 8;
    float p = 0.0f;
    #pragma unroll
    for (int k = 0; k < 8; ++k) p += wr[k] * hv[k];
    #pragma unroll
    for (int m = 1; m < 64; m <<= 1) p += __shfl_xor(p, m);
    o += w2[r] * (p + b1[r]);
  }
  if (lane == 0) out[0] = o + b2[0];
}

extern "C" void kernel_launch(void* const* d_in, const int* in_sizes, int n_in,
                              void* d_out, int out_size, void* d_ws, size_t ws_size,
                              hipStream_t stream)
{
  const float* input_seq = (const float*)d_in[0];
  const float* w_ih0 = (const float*)d_in[1];
  const float* w_hh0 = (const float*)d_in[2];
  const float* b_ih0 = (const float*)d_in[3];
  const float* b_hh0 = (const float*)d_in[4];
  const float* w_ih1 = (const float*)d_in[5];
  const float* w_hh1 = (const float*)d_in[6];
  const float* b_ih1 = (const float*)d_in[7];
  const float* b_hh1 = (const float*)d_in[8];
  const float* w1 = (const float*)d_in[9];
  const float* b1 = (const float*)d_in[10];
  const float* w2 = (const float*)d_in[11];
  const float* b2 = (const float*)d_in[12];
  (void)in_sizes; (void)n_in; (void)out_size; (void)ws_size;

  char* ws = (char*)d_ws;
  float* h0buf = (float*)(ws);                                  // [T][512]
  float* h1buf = (float*)(ws + (size_t)T_SEQ * 512 * 4);        // [T][512]

  hipLaunchKernelGGL(lstm_main, dim3(48), dim3(256), 0, stream,
                     input_seq, w_ih0, w_hh0, b_ih0, b_hh0,
                     w_ih1, w_hh1, b_ih1, b_hh1, h0buf, h1buf);
  hipLaunchKernelGGL(lstm_head, dim3(1), dim3(64), 0, stream,
                     h1buf, w1, b1, w2, b2, (float*)d_out);
}